// Round 11
// baseline (112.888 us; speedup 1.0000x reference)
//
#include <hip/hip_runtime.h>
#include <math.h>

#define D 512
#define NC 64
#define NQ 2048

typedef unsigned short u16;
typedef __attribute__((ext_vector_type(8))) short bf8;
typedef __attribute__((ext_vector_type(4))) float f4;

// ---- workspace float offsets ----
#define OFF_S    0
#define OFF_ABH  32                       // 2560x512 u16 (rows 0-511 Ubp, 512+ Xq) hi
#define OFF_ABL  (OFF_ABH + 655360)
#define OFF_LH   (OFF_ABL + 655360)       // 512x512 u16 L hi/lo
#define OFF_LL   (OFF_LH + 131072)
#define OFF_WH   (OFF_LL + 131072)        // 512x512 u16 W hi/lo (lo valid on diag128 blocks)
#define OFF_WL   (OFF_WH + 131072)
#define OFF_YYH  (OFF_WL + 131072)        // 2560x512 u16 YY hi; lo only rows>=512
#define OFF_YYL  (OFF_YYH + 655360)
#define OFF_AQ   (OFF_YYL + 655360)       // 2048 fp32
#define OFF_GRAM (OFF_AQ + NQ)            // 64*28 fp32 packed upper-tri 7x7 Grams

#define GIX(i, j) ((i) * 7 - (i) * ((i) + 1) / 2 + (j))

__device__ inline float wred(float v) {
#pragma unroll
  for (int off = 32; off; off >>= 1) v += __shfl_down(v, off);
  return v;
}

// split fp32 into hi bf16 (truncated, so v-hi is exact) + lo bf16 (RN)
__device__ inline void split2(float v, u16& h, u16& l) {
  unsigned u = __float_as_uint(v);
  h = (u16)(u >> 16);
  float hf = __uint_as_float(u & 0xFFFF0000u);
  float r = v - hf;
  unsigned ru = __float_as_uint(r);
  l = (u16)((ru + 0x7FFFu + ((ru >> 16) & 1u)) >> 16);
}

#define MPAD 68
template <int N>
__device__ inline void lds_mm(float (*M)[MPAD], int ar, int ac, int br, int bc,
                              int cr, int cc, bool neg) {
  const int T = N / 16;
  int tx = (threadIdx.x & 15) * T, ty = (threadIdx.x >> 4) * T;
  float acc[T][T];
#pragma unroll
  for (int i = 0; i < T; ++i)
#pragma unroll
    for (int j = 0; j < T; ++j) acc[i][j] = 0.f;
#pragma unroll 8
  for (int k = 0; k < N; ++k) {
    float a[T], b[T];
#pragma unroll
    for (int i = 0; i < T; ++i) a[i] = M[ar + ty + i][ac + k];
#pragma unroll
    for (int j = 0; j < T; ++j) b[j] = M[br + k][bc + tx + j];
#pragma unroll
    for (int i = 0; i < T; ++i)
#pragma unroll
      for (int j = 0; j < T; ++j) acc[i][j] += a[i] * b[j];
  }
#pragma unroll
  for (int i = 0; i < T; ++i)
#pragma unroll
    for (int j = 0; j < T; ++j)
      M[cr + ty + i][cc + tx + j] = neg ? -acc[i][j] : acc[i][j];
}

// In-LDS 64x64 lower-tri inversion; on exit M holds exact inverse with ZERO
// upper triangle (scratch regions cleaned between levels).
__device__ inline void inv64(float (*M)[MPAD], int tid) {
  {
    float x[16];
    int q = tid >> 4, col = tid & 15;
    if (tid < 64) {
      int b = q << 4;
#pragma unroll
      for (int i = 0; i < 16; ++i) {
        float acc = 0.f;
#pragma unroll
        for (int k = 0; k < i; ++k) acc += M[b + i][b + k] * x[k];
        x[i] = (((i == col) ? 1.f : 0.f) - acc) / M[b + i][b + i];
      }
    }
    __syncthreads();
    if (tid < 64) {
      int b = q << 4;
#pragma unroll
      for (int i = 0; i < 16; ++i) M[b + i][b + col] = x[i];
    }
    __syncthreads();
  }
  for (int pp = 0; pp < 2; ++pp) {
    int r0 = 32 * pp;
    lds_mm<16>(M, r0 + 16, r0, r0, r0, r0, r0 + 16, false);
  }
  __syncthreads();
  for (int pp = 0; pp < 2; ++pp) {
    int r0 = 32 * pp;
    lds_mm<16>(M, r0 + 16, r0 + 16, r0, r0 + 16, r0 + 16, r0, true);
  }
  __syncthreads();
  for (int idx = tid; idx < 512; idx += 256) {     // zero level-16 scratch
    int t2 = idx >> 8, r = (idx >> 4) & 15, c = idx & 15;
    M[32 * t2 + r][32 * t2 + 16 + c] = 0.f;
  }
  __syncthreads();
  lds_mm<32>(M, 32, 0, 0, 0, 0, 32, false);
  __syncthreads();
  lds_mm<32>(M, 32, 32, 0, 32, 32, 0, true);
  __syncthreads();
  for (int idx = tid; idx < 1024; idx += 256) {    // zero level-32 scratch
    int r = idx >> 5, c = idx & 31;
    M[r][32 + c] = 0.f;
  }
  __syncthreads();
}

// Dst = (+/-) A @ B, all 64x64 LDS buffers, 4x4 micro, 256 threads.
__device__ inline void mm64(float (*Dst)[MPAD], const float (*A)[MPAD],
                            const float (*B)[MPAD], bool neg, int tid) {
  int tx = (tid & 15) * 4, ty = (tid >> 4) * 4;
  float acc[4][4] = {};
#pragma unroll 8
  for (int k = 0; k < 64; ++k) {
    float a[4], b[4];
#pragma unroll
    for (int i = 0; i < 4; ++i) a[i] = A[ty + i][k];
#pragma unroll
    for (int j = 0; j < 4; ++j) b[j] = B[k][tx + j];
#pragma unroll
    for (int i = 0; i < 4; ++i)
#pragma unroll
      for (int j = 0; j < 4; ++j) acc[i][j] += a[i] * b[j];
  }
#pragma unroll
  for (int i = 0; i < 4; ++i)
#pragma unroll
    for (int j = 0; j < 4; ++j)
      Dst[ty + i][tx + j] = neg ? -acc[i][j] : acc[i][j];
}

// Fused prep (1605 blocks):
//   0..1023   : L -> Lh/Ll split; zero W upper (h AND l)
//   1024..1087: classprep -> ABh/ABl rows c*8..
//   1088      : scalars + aq/Gram zero
//   1089..1600: Xq -> ABh/ABl rows 512..
//   1601..1604: invert 128x128 diag block of L -> W diag (h/l), via
//               2x inv64 + X_off = -Binv @ (C @ Ainv)
__global__ __launch_bounds__(256) void k_prep(const float* __restrict__ diag,
                                              const float* __restrict__ low,
                                              const float* __restrict__ Xs,
                                              const float* __restrict__ Xq,
                                              const float* __restrict__ m,
                                              const float* __restrict__ kp,
                                              const float* __restrict__ nup,
                                              u16* __restrict__ Lh, u16* __restrict__ Ll,
                                              u16* __restrict__ ABh, u16* __restrict__ ABl,
                                              u16* __restrict__ Wh, u16* __restrict__ Wl,
                                              float* __restrict__ S, float* __restrict__ aq,
                                              float* __restrict__ Gram) {
  __shared__ float M3[3][64][MPAD];
  int bid = blockIdx.x, tid = threadIdx.x;
  if (bid < 1024) {
    int t = bid * 256 + tid;
    int i = t >> 9, j = t & 511;
    float v = (i == j) ? fabsf(diag[i]) : (i > j ? low[t] : 0.f);
    u16 hh, ll; split2(v, hh, ll);
    Lh[t] = hh; Ll[t] = ll;
    if (i < j) { Wh[t] = 0; Wl[t] = 0; }
  } else if (bid < 1088) {
    int c = bid - 1024;
    float kappa = kp[0];
    float kn = fabsf(kappa) + 1e-6f + 5.0f;
    float xw = 5.0f / kn;
    float mw = fabsf(kappa + 1e-6f) / kn;
    float sw = sqrtf((fabsf(kappa) + 1e-6f) / kn);
    const float is5 = 0.44721359549995793f;
    for (int d = tid; d < D; d += 256) {
      float x[5];
#pragma unroll
      for (int s = 0; s < 5; ++s) x[s] = Xs[(size_t)(c * 5 + s) * D + d];
      float xm = (x[0] + x[1] + x[2] + x[3] + x[4]) * 0.2f;
      float mv = m[d];
      float rowv[8];
#pragma unroll
      for (int s = 0; s < 5; ++s) rowv[s] = x[s] * is5;
      rowv[5] = sw * (xm - mv);
      rowv[6] = mw * mv + xw * xm;
      rowv[7] = 0.f;
#pragma unroll
      for (int s = 0; s < 8; ++s) {
        size_t gi = (size_t)(c * 8 + s) * D + d;
        u16 hh, ll; split2(rowv[s], hh, ll);
        ABh[gi] = hh; ABl[gi] = ll;
      }
    }
  } else if (bid == 1088) {
    for (int i = tid; i < NQ; i += 256) aq[i] = 0.f;
    for (int i = tid; i < NC * 28; i += 256) Gram[i] = 0.f;
    if (tid >= 64) return;
    float part = 0.f;
    for (int i = tid; i < D; i += 64) part += logf(fabsf(diag[i]));
    part = wred(part);
    if (tid != 0) return;
    float lda = 2.f * part;
    float kappa = kp[0], nu = nup[0];
    float kn = fabsf(kappa) + 1e-6f + 5.0f;
    float sp = fmaxf(nu, (float)(D - 1) + 1e-6f) + 5.0f - (float)D + 2.0f;
    float bias_shared = lgammaf(0.5f * (sp + (float)D)) - lgammaf(0.5f * sp)
                      - 0.5f * (float)D * logf(sp);
    float scale = kn * sp / (kn + 1.0f);
    S[3] = bias_shared;
    S[8] = 1.f / scale;
    S[9] = (float)D * logf(scale) + lda;
    S[10] = 0.5f * (sp + (float)D);
    S[11] = 1.f / sp;
  } else if (bid < 1601) {
    int idx = bid - 1089;
    size_t base = (size_t)512 * D + (size_t)idx * 2048;
    for (int i = tid; i < 2048; i += 256) {
      float v = Xq[(size_t)idx * 2048 + i];
      u16 hh, ll; split2(v, hh, ll);
      ABh[base + i] = hh; ABl[base + i] = ll;
    }
  } else {
    int p = (bid - 1601) * 128;
    float (*b0)[MPAD] = M3[0];
    float (*b1)[MPAD] = M3[1];
    float (*b2)[MPAD] = M3[2];
    // load A (upper-left diag 64) -> b0, C (off-diag) -> b1
    for (int idx = tid; idx < 4096; idx += 256) {
      int r = idx >> 6, c = idx & 63;
      b0[r][c] = (r == c) ? fabsf(diag[p + r])
                          : (r > c ? low[(size_t)(p + r) * D + p + c] : 0.f);
      b1[r][c] = low[(size_t)(p + 64 + r) * D + p + c];
    }
    __syncthreads();
    inv64(b0, tid);
    mm64(b2, b1, b0, false, tid);      // T2 = C @ Ainv
    __syncthreads();
    // write Ainv tile (upper already zero)
    for (int idx = tid; idx < 4096; idx += 256) {
      int r = idx >> 6, c = idx & 63;
      u16 hh, ll; split2(b0[r][c], hh, ll);
      size_t gi = (size_t)(p + r) * D + p + c;
      Wh[gi] = hh; Wl[gi] = ll;
    }
    // load B (lower-right diag 64) -> b1
    for (int idx = tid; idx < 4096; idx += 256) {
      int r = idx >> 6, c = idx & 63;
      b1[r][c] = (r == c) ? fabsf(diag[p + 64 + r])
                          : (r > c ? low[(size_t)(p + 64 + r) * D + p + 64 + c] : 0.f);
    }
    __syncthreads();
    inv64(b1, tid);
    mm64(b0, b1, b2, true, tid);       // X_off = -Binv @ T2
    __syncthreads();
    for (int idx = tid; idx < 4096; idx += 256) {
      int r = idx >> 6, c = idx & 63;
      u16 hh, ll;
      split2(b1[r][c], hh, ll);
      size_t gb = (size_t)(p + 64 + r) * D + p + 64 + c;
      Wh[gb] = hh; Wl[gb] = ll;
      split2(b0[r][c], hh, ll);
      size_t gx = (size_t)(p + 64 + r) * D + p + c;
      Wh[gx] = hh; Wl[gx] = ll;
    }
  }
}

// W = L^{-1} column-panel solve at 128-block granularity (<=3 serial steps).
// Panel J (0..11) owns W cols [32J,32J+32); i0 = J>>2. MFMA split-bf16 3-pass.
__global__ __launch_bounds__(256) void k_solve(const u16* __restrict__ Lh,
                                               const u16* __restrict__ Ll,
                                               u16* __restrict__ Wh,
                                               const u16* __restrict__ Wl) {
  __shared__ __align__(16) u16 XTh[32][520];
  __shared__ __align__(16) u16 XTl[32][520];
  __shared__ __align__(16) u16 STh[32][136];
  __shared__ __align__(16) u16 STl[32][136];
  int J = blockIdx.x;
  int i0 = J >> 2, cs = (J & 3) * 32;
  int tid = threadIdx.x, w = tid >> 6, lane = tid & 63;
  int lr = lane & 15, kq = lane >> 4;
  // seed: XT = Dinv128_{i0} column-slice (h/l)
  for (int idx = tid; idx < 128 * 32; idx += 256) {
    int r = idx >> 5, c = idx & 31;
    size_t gi = (size_t)(128 * i0 + r) * D + 128 * i0 + cs + c;
    XTh[c][128 * i0 + r] = Wh[gi];
    XTl[c][128 * i0 + r] = Wl[gi];
  }
  __syncthreads();
  for (int i = i0 + 1; i < 4; ++i) {
    // GEMM1: S = sum_k L128_{i,k} @ X_k   (wave w -> rows 32w..32w+32)
    f4 acc[2][2];
#pragma unroll
    for (int mi = 0; mi < 2; ++mi)
#pragma unroll
      for (int nf = 0; nf < 2; ++nf) acc[mi][nf] = (f4){0.f, 0.f, 0.f, 0.f};
    for (int k = i0; k < i; ++k) {
#pragma unroll
      for (int kf = 0; kf < 4; ++kf) {
#pragma unroll
        for (int mi = 0; mi < 2; ++mi) {
          size_t ga = (size_t)(128 * i + (2 * w + mi) * 16 + lr) * D + 128 * k + kf * 32 + kq * 8;
          bf8 ah = *reinterpret_cast<const bf8*>(Lh + ga);
          bf8 al = *reinterpret_cast<const bf8*>(Ll + ga);
#pragma unroll
          for (int nf = 0; nf < 2; ++nf) {
            bf8 bh = *reinterpret_cast<const bf8*>(&XTh[nf * 16 + lr][128 * k + kf * 32 + kq * 8]);
            bf8 bl = *reinterpret_cast<const bf8*>(&XTl[nf * 16 + lr][128 * k + kf * 32 + kq * 8]);
            acc[mi][nf] = __builtin_amdgcn_mfma_f32_16x16x32_bf16(ah, bh, acc[mi][nf], 0, 0, 0);
            acc[mi][nf] = __builtin_amdgcn_mfma_f32_16x16x32_bf16(ah, bl, acc[mi][nf], 0, 0, 0);
            acc[mi][nf] = __builtin_amdgcn_mfma_f32_16x16x32_bf16(al, bh, acc[mi][nf], 0, 0, 0);
          }
        }
      }
    }
    // ST = -S^T
#pragma unroll
    for (int mi = 0; mi < 2; ++mi)
#pragma unroll
      for (int nf = 0; nf < 2; ++nf)
#pragma unroll
        for (int reg = 0; reg < 4; ++reg) {
          float v = -acc[mi][nf][reg];
          u16 hh, ll; split2(v, hh, ll);
          int rl = (2 * w + mi) * 16 + kq * 4 + reg, cl = nf * 16 + lr;
          STh[cl][rl] = hh; STl[cl][rl] = ll;
        }
    __syncthreads();
    // GEMM2: X_i = Dinv128_i @ (-S)
    f4 acc2[2][2];
#pragma unroll
    for (int mi = 0; mi < 2; ++mi)
#pragma unroll
      for (int nf = 0; nf < 2; ++nf) acc2[mi][nf] = (f4){0.f, 0.f, 0.f, 0.f};
#pragma unroll
    for (int kf = 0; kf < 4; ++kf) {
#pragma unroll
      for (int mi = 0; mi < 2; ++mi) {
        size_t ga = (size_t)(128 * i + (2 * w + mi) * 16 + lr) * D + 128 * i + kf * 32 + kq * 8;
        bf8 ah = *reinterpret_cast<const bf8*>(Wh + ga);
        bf8 al = *reinterpret_cast<const bf8*>(Wl + ga);
#pragma unroll
        for (int nf = 0; nf < 2; ++nf) {
          bf8 bh = *reinterpret_cast<const bf8*>(&STh[nf * 16 + lr][kf * 32 + kq * 8]);
          bf8 bl = *reinterpret_cast<const bf8*>(&STl[nf * 16 + lr][kf * 32 + kq * 8]);
          acc2[mi][nf] = __builtin_amdgcn_mfma_f32_16x16x32_bf16(ah, bh, acc2[mi][nf], 0, 0, 0);
          acc2[mi][nf] = __builtin_amdgcn_mfma_f32_16x16x32_bf16(ah, bl, acc2[mi][nf], 0, 0, 0);
          acc2[mi][nf] = __builtin_amdgcn_mfma_f32_16x16x32_bf16(al, bh, acc2[mi][nf], 0, 0, 0);
        }
      }
    }
#pragma unroll
    for (int mi = 0; mi < 2; ++mi)
#pragma unroll
      for (int nf = 0; nf < 2; ++nf)
#pragma unroll
        for (int reg = 0; reg < 4; ++reg) {
          float v = acc2[mi][nf][reg];
          u16 hh, ll; split2(v, hh, ll);
          int rl = (2 * w + mi) * 16 + kq * 4 + reg, cl = nf * 16 + lr;
          Wh[(size_t)(128 * i + rl) * D + 32 * J + cl] = hh;
          XTh[cl][128 * i + rl] = hh; XTl[cl][128 * i + rl] = ll;
        }
    __syncthreads();
  }
}

// GEMM1 (MFMA split-bf16, 2-pass hh+lh): YY = [Ubp;Xq] @ W^T, tri-clipped.
// Grid (8,40), heavy n-strips first. Fused: YYh (all), YYl (Y rows), aq, Grams.
__global__ __launch_bounds__(256) void k_mf1(const u16* __restrict__ ABh, const u16* __restrict__ ABl,
                                             const u16* __restrict__ Wh,
                                             u16* __restrict__ YYh, u16* __restrict__ YYl,
                                             float* __restrict__ Gram, float* __restrict__ aq) {
  __shared__ float Csh[64][68];
  int tid = threadIdx.x, w = tid >> 6, lane = tid & 63;
  int bn = (7 - (int)blockIdx.x) * 64;
  int m0 = blockIdx.y * 64 + w * 16;
  int lr = lane & 15, kof = (lane >> 4) * 8;
  const u16* ah_p = ABh + (size_t)(m0 + lr) * D + kof;
  const u16* al_p = ABl + (size_t)(m0 + lr) * D + kof;
  const u16* bh_p = Wh + (size_t)(bn + lr) * D + kof;
  f4 acc[4];
#pragma unroll
  for (int nf = 0; nf < 4; ++nf) acc[nf] = (f4){0.f, 0.f, 0.f, 0.f};
  int Klim = bn + 64;
#pragma unroll 2
  for (int k0 = 0; k0 < Klim; k0 += 32) {
    bf8 ah = *reinterpret_cast<const bf8*>(ah_p + k0);
    bf8 al = *reinterpret_cast<const bf8*>(al_p + k0);
    bf8 bh[4];
#pragma unroll
    for (int nf = 0; nf < 4; ++nf)
      bh[nf] = *reinterpret_cast<const bf8*>(bh_p + (size_t)nf * 16 * D + k0);
#pragma unroll
    for (int nf = 0; nf < 4; ++nf)
      acc[nf] = __builtin_amdgcn_mfma_f32_16x16x32_bf16(ah, bh[nf], acc[nf], 0, 0, 0);
#pragma unroll
    for (int nf = 0; nf < 4; ++nf)
      acc[nf] = __builtin_amdgcn_mfma_f32_16x16x32_bf16(al, bh[nf], acc[nf], 0, 0, 0);
  }
  int rbase = m0 + ((lane >> 4) << 2);
#pragma unroll
  for (int reg = 0; reg < 4; ++reg) {
    int row = rbase + reg;
    float sq = 0.f;
#pragma unroll
    for (int nf = 0; nf < 4; ++nf) {
      float v = acc[nf][reg];
      size_t gi = (size_t)row * D + bn + nf * 16 + lr;
      u16 hh, ll; split2(v, hh, ll);
      YYh[gi] = hh;
      if (row >= 512) YYl[gi] = ll;
      sq += v * v;
    }
    if (row >= 512) {
#pragma unroll
      for (int mk = 1; mk < 16; mk <<= 1) sq += __shfl_xor(sq, mk);
      if (lr == 0) atomicAdd(&aq[row - 512], sq);
    }
  }
  if (blockIdx.y < 8) {
#pragma unroll
    for (int reg = 0; reg < 4; ++reg)
#pragma unroll
      for (int nf = 0; nf < 4; ++nf)
        Csh[w * 16 + ((lane >> 4) << 2) + reg][nf * 16 + lr] = acc[nf][reg];
    __syncthreads();
    if (tid < 224) {
      const int PI[28] = {0,0,0,0,0,0,0, 1,1,1,1,1,1, 2,2,2,2,2, 3,3,3,3, 4,4,4, 5,5, 6};
      const int PJ[28] = {0,1,2,3,4,5,6, 1,2,3,4,5,6, 2,3,4,5,6, 3,4,5,6, 4,5,6, 5,6, 6};
      int cl = tid / 28, p = tid % 28;
      const float* ri = Csh[cl * 8 + PI[p]];
      const float* rj = Csh[cl * 8 + PJ[p]];
      float s = 0.f;
#pragma unroll
      for (int c4 = 0; c4 < 64; c4 += 4) {
        float4 a = *reinterpret_cast<const float4*>(&ri[c4]);
        float4 b = *reinterpret_cast<const float4*>(&rj[c4]);
        s += a.x * b.x + a.y * b.y + a.z * b.z + a.w * b.w;
      }
      atomicAdd(&Gram[(blockIdx.y * 8 + cl) * 28 + p], s);
    }
  }
}

// GEMM2 (MFMA split-bf16, 2-pass) + per-block Cholesky prologue + fused epilogue.
__global__ __launch_bounds__(256) void k_mf2(const u16* __restrict__ Yh, const u16* __restrict__ Yl,
                                             const u16* __restrict__ Bh,
                                             const float* __restrict__ aq,
                                             const float* __restrict__ Gram,
                                             const float* __restrict__ S,
                                             float* __restrict__ out) {
  __shared__ float Csh[4][16][68];
  __shared__ float PRo[8][15], PRd[8][6], Psv[8][6], Pb[8], Ph[8];
  int tid = threadIdx.x, w = tid >> 6, lane = tid & 63;
  int m0 = blockIdx.x * 64 + w * 16;
  int bn = blockIdx.y * 64;
  int lr = lane & 15, kof = (lane >> 4) * 8;
  const u16* ah_p = Yh + (size_t)(m0 + lr) * D + kof;
  const u16* al_p = Yl + (size_t)(m0 + lr) * D + kof;
  const u16* bh_p = Bh + (size_t)(bn + lr) * D + kof;
  f4 acc[4];
#pragma unroll
  for (int nf = 0; nf < 4; ++nf) acc[nf] = (f4){0.f, 0.f, 0.f, 0.f};
#pragma unroll 2
  for (int k0 = 0; k0 < D; k0 += 32) {
    bf8 ah = *reinterpret_cast<const bf8*>(ah_p + k0);
    bf8 al = *reinterpret_cast<const bf8*>(al_p + k0);
    bf8 bh[4];
#pragma unroll
    for (int nf = 0; nf < 4; ++nf)
      bh[nf] = *reinterpret_cast<const bf8*>(bh_p + (size_t)nf * 16 * D + k0);
#pragma unroll
    for (int nf = 0; nf < 4; ++nf)
      acc[nf] = __builtin_amdgcn_mfma_f32_16x16x32_bf16(ah, bh[nf], acc[nf], 0, 0, 0);
#pragma unroll
    for (int nf = 0; nf < 4; ++nf)
      acc[nf] = __builtin_amdgcn_mfma_f32_16x16x32_bf16(al, bh[nf], acc[nf], 0, 0, 0);
  }
#pragma unroll
  for (int reg = 0; reg < 4; ++reg)
#pragma unroll
    for (int nf = 0; nf < 4; ++nf)
      Csh[w][((lane >> 4) << 2) + reg][nf * 16 + lr] = acc[nf][reg];
  if (tid < 8) {
    int c = blockIdx.y * 8 + tid;
    float Gv[28];
#pragma unroll
    for (int p = 0; p < 28; ++p) Gv[p] = Gram[c * 28 + p];
    float R[6][6];
    float logdetM = 0.f;
#pragma unroll
    for (int i = 0; i < 6; ++i) {
      float s = Gv[GIX(i, i)] + 1.f;
#pragma unroll
      for (int k = 0; k < i; ++k) s -= R[i][k] * R[i][k];
      float rii = sqrtf(s);
      R[i][i] = rii;
      logdetM += logf(rii);
      float inv = 1.f / rii;
      PRd[tid][i] = inv;
#pragma unroll
      for (int r = i + 1; r < 6; ++r) {
        float s2 = Gv[GIX(i, r)];
#pragma unroll
        for (int k = 0; k < i; ++k) s2 -= R[r][k] * R[i][k];
        R[r][i] = s2 * inv;
      }
    }
#pragma unroll
    for (int i = 1; i < 6; ++i)
#pragma unroll
      for (int k = 0; k < i; ++k)
        PRo[tid][i * (i - 1) / 2 + k] = R[i][k];
#pragma unroll
    for (int j = 0; j < 6; ++j) Psv[tid][j] = Gv[GIX(j, 6)];
    Ph[tid] = Gv[27];
    Pb[tid] = S[3] - 0.5f * (S[9] + 2.f * logdetM);
  }
  __syncthreads();
  float s8 = S[8], s10 = S[10], s11 = S[11];
  int r = lr;
  int q = m0 + r;
  float aqv = aq[q];
#pragma unroll
  for (int cc = 0; cc < 2; ++cc) {
    int cl = ((lane >> 4) << 1) + cc;
    const float* t = &Csh[w][r][cl * 8];
    float e[6];
#pragma unroll
    for (int j = 0; j < 6; ++j) e[j] = t[j] - Psv[cl][j];
    const float* o = PRo[cl];
    const float* dg = PRd[cl];
    float z0 = e[0] * dg[0];
    float z1 = (e[1] - o[0] * z0) * dg[1];
    float z2 = (e[2] - o[1] * z0 - o[2] * z1) * dg[2];
    float z3 = (e[3] - o[3] * z0 - o[4] * z1 - o[5] * z2) * dg[3];
    float z4 = (e[4] - o[6] * z0 - o[7] * z1 - o[8] * z2 - o[9] * z3) * dg[4];
    float z5 = (e[5] - o[10] * z0 - o[11] * z1 - o[12] * z2 - o[13] * z3 - o[14] * z4) * dg[5];
    float quad = z0 * z0 + z1 * z1 + z2 * z2 + z3 * z3 + z4 * z4 + z5 * z5;
    float dist = (aqv - 2.f * t[6] + Ph[cl] - quad) * s8;
    out[(size_t)q * NC + blockIdx.y * 8 + cl] = Pb[cl] - s10 * log1pf(dist * s11);
  }
}

extern "C" void kernel_launch(void* const* d_in, const int* in_sizes, int n_in,
                              void* d_out, int out_size, void* d_ws, size_t ws_size,
                              hipStream_t stream) {
  const float* Xs   = (const float*)d_in[0];
  const float* Xq   = (const float*)d_in[2];
  const float* m    = (const float*)d_in[3];
  const float* kap  = (const float*)d_in[4];
  const float* nu   = (const float*)d_in[5];
  const float* diag = (const float*)d_in[6];
  const float* low  = (const float*)d_in[7];
  float* ws = (float*)d_ws;

  float* S    = ws + OFF_S;
  u16*   ABh  = (u16*)(ws + OFF_ABH);
  u16*   ABl  = (u16*)(ws + OFF_ABL);
  u16*   Lh   = (u16*)(ws + OFF_LH);
  u16*   Ll   = (u16*)(ws + OFF_LL);
  u16*   Wh   = (u16*)(ws + OFF_WH);
  u16*   Wl   = (u16*)(ws + OFF_WL);
  u16*   YYh  = (u16*)(ws + OFF_YYH);
  u16*   YYl  = (u16*)(ws + OFF_YYL);
  float* aq   = ws + OFF_AQ;
  float* Gram = ws + OFF_GRAM;

  hipLaunchKernelGGL(k_prep, dim3(1605), dim3(256), 0, stream,
                     diag, low, Xs, Xq, m, kap, nu, Lh, Ll, ABh, ABl, Wh, Wl, S, aq, Gram);
  hipLaunchKernelGGL(k_solve, dim3(12), dim3(256), 0, stream, Lh, Ll, Wh, Wl);
  // GEMM1: YY = [Ubp;Xq] @ W^T (tri-clipped) + aq + class Grams
  hipLaunchKernelGGL(k_mf1, dim3(8, 40), dim3(256), 0, stream,
                     ABh, ABl, Wh, YYh, YYl, Gram, aq);
  // GEMM2: out = epilogue(Y @ UWp^T) with per-block Cholesky prologue
  hipLaunchKernelGGL(k_mf2, dim3(32, 8), dim3(256), 0, stream,
                     YYh + (size_t)512 * D, YYl + (size_t)512 * D, YYh,
                     aq, Gram, S, (float*)d_out);
}

// Round 12
// 88.792 us; speedup vs baseline: 1.2714x; 1.2714x over previous
//
#include <hip/hip_runtime.h>
#include <math.h>

#define D 512
#define NC 64
#define NQ 2048

typedef unsigned short u16;
typedef __attribute__((ext_vector_type(8))) short bf8;
typedef __attribute__((ext_vector_type(4))) float f4;

// ---- workspace float offsets ----
#define OFF_S    0
#define OFF_ABH  32                       // 2560x512 u16 (rows 0-511 Ubp, 512+ Xq) hi
#define OFF_ABL  (OFF_ABH + 655360)
#define OFF_LH   (OFF_ABL + 655360)       // 512x512 u16 L hi/lo
#define OFF_LL   (OFF_LH + 131072)
#define OFF_WH   (OFF_LL + 131072)        // 512x512 u16 W hi/lo (lo valid on diag64 blocks)
#define OFF_WL   (OFF_WH + 131072)
#define OFF_YYH  (OFF_WL + 131072)        // 2560x512 u16 YY hi; lo only rows>=512
#define OFF_YYL  (OFF_YYH + 655360)
#define OFF_AQ   (OFF_YYL + 655360)       // 2048 fp32
#define OFF_GRAM (OFF_AQ + NQ)            // 64*28 fp32 packed upper-tri 7x7 Grams

#define GIX(i, j) ((i) * 7 - (i) * ((i) + 1) / 2 + (j))

__device__ inline float wred(float v) {
#pragma unroll
  for (int off = 32; off; off >>= 1) v += __shfl_down(v, off);
  return v;
}

// split fp32 into hi bf16 (truncated, so v-hi is exact) + lo bf16 (RN)
__device__ inline void split2(float v, u16& h, u16& l) {
  unsigned u = __float_as_uint(v);
  h = (u16)(u >> 16);
  float hf = __uint_as_float(u & 0xFFFF0000u);
  float r = v - hf;
  unsigned ru = __float_as_uint(r);
  l = (u16)((ru + 0x7FFFu + ((ru >> 16) & 1u)) >> 16);
}

__device__ inline void split4(float a0, float a1, float a2, float a3,
                              ushort4& h, ushort4& l) {
  u16 hh, ll;
  split2(a0, hh, ll); h.x = hh; l.x = ll;
  split2(a1, hh, ll); h.y = hh; l.y = ll;
  split2(a2, hh, ll); h.z = hh; l.z = ll;
  split2(a3, hh, ll); h.w = hh; l.w = ll;
}

#define MPAD 68
template <int N>
__device__ inline void lds_mm(float (*M)[MPAD], int ar, int ac, int br, int bc,
                              int cr, int cc, bool neg) {
  const int T = N / 16;
  int tx = (threadIdx.x & 15) * T, ty = (threadIdx.x >> 4) * T;
  float acc[T][T];
#pragma unroll
  for (int i = 0; i < T; ++i)
#pragma unroll
    for (int j = 0; j < T; ++j) acc[i][j] = 0.f;
#pragma unroll 8
  for (int k = 0; k < N; ++k) {
    float a[T], b[T];
#pragma unroll
    for (int i = 0; i < T; ++i) a[i] = M[ar + ty + i][ac + k];
#pragma unroll
    for (int j = 0; j < T; ++j) b[j] = M[br + k][bc + tx + j];
#pragma unroll
    for (int i = 0; i < T; ++i)
#pragma unroll
      for (int j = 0; j < T; ++j) acc[i][j] += a[i] * b[j];
  }
#pragma unroll
  for (int i = 0; i < T; ++i)
#pragma unroll
    for (int j = 0; j < T; ++j)
      M[cr + ty + i][cc + tx + j] = neg ? -acc[i][j] : acc[i][j];
}

// In-LDS 64x64 lower-tri inversion; scratch cleaned -> exact inverse, zero upper.
__device__ inline void inv64(float (*M)[MPAD], int tid) {
  {
    float x[16];
    int q = tid >> 4, col = tid & 15;
    if (tid < 64) {
      int b = q << 4;
#pragma unroll
      for (int i = 0; i < 16; ++i) {
        float acc = 0.f;
#pragma unroll
        for (int k = 0; k < i; ++k) acc += M[b + i][b + k] * x[k];
        x[i] = (((i == col) ? 1.f : 0.f) - acc) / M[b + i][b + i];
      }
    }
    __syncthreads();
    if (tid < 64) {
      int b = q << 4;
#pragma unroll
      for (int i = 0; i < 16; ++i) M[b + i][b + col] = x[i];
    }
    __syncthreads();
  }
  for (int pp = 0; pp < 2; ++pp) {
    int r0 = 32 * pp;
    lds_mm<16>(M, r0 + 16, r0, r0, r0, r0, r0 + 16, false);
  }
  __syncthreads();
  for (int pp = 0; pp < 2; ++pp) {
    int r0 = 32 * pp;
    lds_mm<16>(M, r0 + 16, r0 + 16, r0, r0 + 16, r0 + 16, r0, true);
  }
  __syncthreads();
  for (int idx = tid; idx < 512; idx += 256) {     // zero level-16 scratch
    int t2 = idx >> 8, r = (idx >> 4) & 15, c = idx & 15;
    M[32 * t2 + r][32 * t2 + 16 + c] = 0.f;
  }
  __syncthreads();
  lds_mm<32>(M, 32, 0, 0, 0, 0, 32, false);
  __syncthreads();
  lds_mm<32>(M, 32, 32, 0, 32, 32, 0, true);
  __syncthreads();
  for (int idx = tid; idx < 1024; idx += 256) {    // zero level-32 scratch
    int r = idx >> 5, c = idx & 31;
    M[r][32 + c] = 0.f;
  }
  __syncthreads();
}

// Fused prep (457 blocks, heavy roles FIRST):
//   0..7    : invert 64x64 diag block of L in LDS -> W diag (h/l)
//   8..71   : classprep -> ABh/ABl rows c*8.. (float4 vectorized)
//   72      : scalars + aq/Gram zero
//   73..328 : L -> Lh/Ll split (float4 -> ushort4)
//   329..456: Xq -> ABh/ABl rows 512.. (float4 -> ushort4)
__global__ __launch_bounds__(256) void k_prep(const float* __restrict__ diag,
                                              const float* __restrict__ low,
                                              const float* __restrict__ Xs,
                                              const float* __restrict__ Xq,
                                              const float* __restrict__ m,
                                              const float* __restrict__ kp,
                                              const float* __restrict__ nup,
                                              u16* __restrict__ Lh, u16* __restrict__ Ll,
                                              u16* __restrict__ ABh, u16* __restrict__ ABl,
                                              u16* __restrict__ Wh, u16* __restrict__ Wl,
                                              float* __restrict__ S, float* __restrict__ aq,
                                              float* __restrict__ Gram) {
  __shared__ float M[64][MPAD];
  int bid = blockIdx.x, tid = threadIdx.x;
  if (bid < 8) {
    int p = bid * 64;
    for (int idx = tid; idx < 4096; idx += 256) {
      int r = idx >> 6, c = idx & 63;
      float v;
      if (r == c)      v = fabsf(diag[p + r]);
      else if (r > c)  v = low[(size_t)(p + r) * D + p + c];
      else             v = 0.f;
      M[r][c] = v;
    }
    __syncthreads();
    inv64(M, tid);
    for (int idx = tid; idx < 1024; idx += 256) {
      int r = idx >> 4, c4 = (idx & 15) << 2;
      ushort4 hh, ll;
      split4(M[r][c4 + 0], M[r][c4 + 1], M[r][c4 + 2], M[r][c4 + 3], hh, ll);
      size_t gi = (size_t)(p + r) * D + p + c4;
      *reinterpret_cast<ushort4*>(Wh + gi) = hh;
      *reinterpret_cast<ushort4*>(Wl + gi) = ll;
    }
  } else if (bid < 72) {
    int c = bid - 8;
    if (tid < 128) {
      float kappa = kp[0];
      float kn = fabsf(kappa) + 1e-6f + 5.0f;
      float xw = 5.0f / kn;
      float mw = fabsf(kappa + 1e-6f) / kn;
      float sw = sqrtf((fabsf(kappa) + 1e-6f) / kn);
      const float is5 = 0.44721359549995793f;
      int d4 = tid;                       // float4 index; d = 4*tid
      float xs[5][4];
#pragma unroll
      for (int s = 0; s < 5; ++s) {
        float4 v = reinterpret_cast<const float4*>(Xs + (size_t)(c * 5 + s) * D)[d4];
        xs[s][0] = v.x; xs[s][1] = v.y; xs[s][2] = v.z; xs[s][3] = v.w;
      }
      float4 mvv = reinterpret_cast<const float4*>(m)[d4];
      float mv[4] = {mvv.x, mvv.y, mvv.z, mvv.w};
      float rows[8][4];
#pragma unroll
      for (int e = 0; e < 4; ++e) {
        float xm = (xs[0][e] + xs[1][e] + xs[2][e] + xs[3][e] + xs[4][e]) * 0.2f;
#pragma unroll
        for (int s = 0; s < 5; ++s) rows[s][e] = xs[s][e] * is5;
        rows[5][e] = sw * (xm - mv[e]);
        rows[6][e] = mw * mv[e] + xw * xm;
        rows[7][e] = 0.f;
      }
#pragma unroll
      for (int s = 0; s < 8; ++s) {
        ushort4 hh, ll;
        split4(rows[s][0], rows[s][1], rows[s][2], rows[s][3], hh, ll);
        size_t gi = (size_t)(c * 8 + s) * D + 4 * tid;
        *reinterpret_cast<ushort4*>(ABh + gi) = hh;
        *reinterpret_cast<ushort4*>(ABl + gi) = ll;
      }
    }
  } else if (bid == 72) {
    for (int i = tid; i < NQ; i += 256) aq[i] = 0.f;
    for (int i = tid; i < NC * 28; i += 256) Gram[i] = 0.f;
    if (tid >= 64) return;
    float part = 0.f;
    for (int i = tid; i < D; i += 64) part += logf(fabsf(diag[i]));
    part = wred(part);
    if (tid != 0) return;
    float lda = 2.f * part;
    float kappa = kp[0], nu = nup[0];
    float kn = fabsf(kappa) + 1e-6f + 5.0f;
    float sp = fmaxf(nu, (float)(D - 1) + 1e-6f) + 5.0f - (float)D + 2.0f;
    float bias_shared = lgammaf(0.5f * (sp + (float)D)) - lgammaf(0.5f * sp)
                      - 0.5f * (float)D * logf(sp);
    float scale = kn * sp / (kn + 1.0f);
    S[3] = bias_shared;
    S[8] = 1.f / scale;
    S[9] = (float)D * logf(scale) + lda;
    S[10] = 0.5f * (sp + (float)D);
    S[11] = 1.f / sp;
  } else if (bid < 329) {
    int t = (bid - 73) * 1024 + tid * 4;
    int i = t >> 9, j = t & 511;
    float4 lv = *reinterpret_cast<const float4*>(low + t);
    float a[4] = {lv.x, lv.y, lv.z, lv.w};
    float dv = diag[i];
    float o[4];
#pragma unroll
    for (int e = 0; e < 4; ++e) {
      int jj = j + e;
      o[e] = (i == jj) ? fabsf(dv) : (i > jj ? a[e] : 0.f);
    }
    ushort4 hh, ll;
    split4(o[0], o[1], o[2], o[3], hh, ll);
    *reinterpret_cast<ushort4*>(Lh + t) = hh;
    *reinterpret_cast<ushort4*>(Ll + t) = ll;
  } else {
    size_t base = (size_t)(bid - 329) * 8192;
#pragma unroll
    for (int it = 0; it < 8; ++it) {
      size_t idx = base + it * 1024 + tid * 4;
      float4 v = *reinterpret_cast<const float4*>(Xq + idx);
      ushort4 hh, ll;
      split4(v.x, v.y, v.z, v.w, hh, ll);
      *reinterpret_cast<ushort4*>(ABh + (size_t)512 * D + idx) = hh;
      *reinterpret_cast<ushort4*>(ABl + (size_t)512 * D + idx) = ll;
    }
  }
}

// W = L^{-1} column-panel solve, 64-row granularity (proven R10 structure).
// Panel J (0..15) owns W cols [32J,32J+32); i0 = J>>1. MFMA split-bf16 3-pass.
__global__ __launch_bounds__(256) void k_solve(const u16* __restrict__ Lh,
                                               const u16* __restrict__ Ll,
                                               u16* __restrict__ Wh,
                                               const u16* __restrict__ Wl) {
  __shared__ __align__(16) u16 XTh[32][520];
  __shared__ __align__(16) u16 XTl[32][520];
  __shared__ __align__(16) u16 STh[32][72];
  __shared__ __align__(16) u16 STl[32][72];
  int J = blockIdx.x;
  int i0 = J >> 1;
  int tid = threadIdx.x, w = tid >> 6, lane = tid & 63;
  int lr = lane & 15, kq = lane >> 4;
  for (int idx = tid; idx < 64 * 32; idx += 256) {
    int r = idx >> 5, c = idx & 31;
    size_t gi = (size_t)(64 * i0 + r) * D + 64 * i0 + (J & 1) * 32 + c;
    XTh[c][64 * i0 + r] = Wh[gi];
    XTl[c][64 * i0 + r] = Wl[gi];
  }
  __syncthreads();
  for (int i = i0 + 1; i < 8; ++i) {
    f4 acc[2];
    acc[0] = (f4){0.f, 0.f, 0.f, 0.f};
    acc[1] = (f4){0.f, 0.f, 0.f, 0.f};
    for (int k = i0; k < i; ++k) {
#pragma unroll
      for (int kk = 0; kk < 2; ++kk) {
        size_t ga = (size_t)(64 * i + w * 16 + lr) * D + 64 * k + kk * 32 + kq * 8;
        bf8 ah = *reinterpret_cast<const bf8*>(Lh + ga);
        bf8 al = *reinterpret_cast<const bf8*>(Ll + ga);
#pragma unroll
        for (int nf = 0; nf < 2; ++nf) {
          bf8 bh = *reinterpret_cast<const bf8*>(&XTh[nf * 16 + lr][64 * k + kk * 32 + kq * 8]);
          bf8 bl = *reinterpret_cast<const bf8*>(&XTl[nf * 16 + lr][64 * k + kk * 32 + kq * 8]);
          acc[nf] = __builtin_amdgcn_mfma_f32_16x16x32_bf16(ah, bh, acc[nf], 0, 0, 0);
          acc[nf] = __builtin_amdgcn_mfma_f32_16x16x32_bf16(ah, bl, acc[nf], 0, 0, 0);
          acc[nf] = __builtin_amdgcn_mfma_f32_16x16x32_bf16(al, bh, acc[nf], 0, 0, 0);
        }
      }
    }
#pragma unroll
    for (int nf = 0; nf < 2; ++nf)
#pragma unroll
      for (int reg = 0; reg < 4; ++reg) {
        float v = -acc[nf][reg];
        u16 hh, ll; split2(v, hh, ll);
        int c = nf * 16 + lr, r = w * 16 + kq * 4 + reg;
        STh[c][r] = hh; STl[c][r] = ll;
      }
    __syncthreads();
    f4 acc2[2];
    acc2[0] = (f4){0.f, 0.f, 0.f, 0.f};
    acc2[1] = (f4){0.f, 0.f, 0.f, 0.f};
#pragma unroll
    for (int kk = 0; kk < 2; ++kk) {
      size_t ga = (size_t)(64 * i + w * 16 + lr) * D + 64 * i + kk * 32 + kq * 8;
      bf8 ah = *reinterpret_cast<const bf8*>(Wh + ga);
      bf8 al = *reinterpret_cast<const bf8*>(Wl + ga);
#pragma unroll
      for (int nf = 0; nf < 2; ++nf) {
        bf8 bh = *reinterpret_cast<const bf8*>(&STh[nf * 16 + lr][kk * 32 + kq * 8]);
        bf8 bl = *reinterpret_cast<const bf8*>(&STl[nf * 16 + lr][kk * 32 + kq * 8]);
        acc2[nf] = __builtin_amdgcn_mfma_f32_16x16x32_bf16(ah, bh, acc2[nf], 0, 0, 0);
        acc2[nf] = __builtin_amdgcn_mfma_f32_16x16x32_bf16(ah, bl, acc2[nf], 0, 0, 0);
        acc2[nf] = __builtin_amdgcn_mfma_f32_16x16x32_bf16(al, bh, acc2[nf], 0, 0, 0);
      }
    }
#pragma unroll
    for (int nf = 0; nf < 2; ++nf)
#pragma unroll
      for (int reg = 0; reg < 4; ++reg) {
        float v = acc2[nf][reg];
        u16 hh, ll; split2(v, hh, ll);
        int r = w * 16 + kq * 4 + reg, c = nf * 16 + lr;
        Wh[(size_t)(64 * i + r) * D + 32 * J + c] = hh;
        XTh[c][64 * i + r] = hh; XTl[c][64 * i + r] = ll;
      }
    __syncthreads();
  }
}

// GEMM1 (MFMA split-bf16, 2-pass hh+lh): YY = [Ubp;Xq] @ W^T, tri-clipped.
// Grid (8,40), heavy n-strips first. Fused: YYh (all), YYl (Y rows), aq, Grams.
__global__ __launch_bounds__(256) void k_mf1(const u16* __restrict__ ABh, const u16* __restrict__ ABl,
                                             const u16* __restrict__ Wh,
                                             u16* __restrict__ YYh, u16* __restrict__ YYl,
                                             float* __restrict__ Gram, float* __restrict__ aq) {
  __shared__ float Csh[64][68];
  int tid = threadIdx.x, w = tid >> 6, lane = tid & 63;
  int bn = (7 - (int)blockIdx.x) * 64;
  int m0 = blockIdx.y * 64 + w * 16;
  int lr = lane & 15, kof = (lane >> 4) * 8;
  const u16* ah_p = ABh + (size_t)(m0 + lr) * D + kof;
  const u16* al_p = ABl + (size_t)(m0 + lr) * D + kof;
  const u16* bh_p = Wh + (size_t)(bn + lr) * D + kof;
  f4 acc[4];
#pragma unroll
  for (int nf = 0; nf < 4; ++nf) acc[nf] = (f4){0.f, 0.f, 0.f, 0.f};
  int Klim = bn + 64;
#pragma unroll 2
  for (int k0 = 0; k0 < Klim; k0 += 32) {
    bf8 ah = *reinterpret_cast<const bf8*>(ah_p + k0);
    bf8 al = *reinterpret_cast<const bf8*>(al_p + k0);
    bf8 bh[4];
#pragma unroll
    for (int nf = 0; nf < 4; ++nf)
      bh[nf] = *reinterpret_cast<const bf8*>(bh_p + (size_t)nf * 16 * D + k0);
#pragma unroll
    for (int nf = 0; nf < 4; ++nf)
      acc[nf] = __builtin_amdgcn_mfma_f32_16x16x32_bf16(ah, bh[nf], acc[nf], 0, 0, 0);
#pragma unroll
    for (int nf = 0; nf < 4; ++nf)
      acc[nf] = __builtin_amdgcn_mfma_f32_16x16x32_bf16(al, bh[nf], acc[nf], 0, 0, 0);
  }
  int rbase = m0 + ((lane >> 4) << 2);
#pragma unroll
  for (int reg = 0; reg < 4; ++reg) {
    int row = rbase + reg;
    float sq = 0.f;
#pragma unroll
    for (int nf = 0; nf < 4; ++nf) {
      float v = acc[nf][reg];
      size_t gi = (size_t)row * D + bn + nf * 16 + lr;
      u16 hh, ll; split2(v, hh, ll);
      YYh[gi] = hh;
      if (row >= 512) YYl[gi] = ll;
      sq += v * v;
    }
    if (row >= 512) {
#pragma unroll
      for (int mk = 1; mk < 16; mk <<= 1) sq += __shfl_xor(sq, mk);
      if (lr == 0) atomicAdd(&aq[row - 512], sq);
    }
  }
  if (blockIdx.y < 8) {
#pragma unroll
    for (int reg = 0; reg < 4; ++reg)
#pragma unroll
      for (int nf = 0; nf < 4; ++nf)
        Csh[w * 16 + ((lane >> 4) << 2) + reg][nf * 16 + lr] = acc[nf][reg];
    __syncthreads();
    if (tid < 224) {
      const int PI[28] = {0,0,0,0,0,0,0, 1,1,1,1,1,1, 2,2,2,2,2, 3,3,3,3, 4,4,4, 5,5, 6};
      const int PJ[28] = {0,1,2,3,4,5,6, 1,2,3,4,5,6, 2,3,4,5,6, 3,4,5,6, 4,5,6, 5,6, 6};
      int cl = tid / 28, p = tid % 28;
      const float* ri = Csh[cl * 8 + PI[p]];
      const float* rj = Csh[cl * 8 + PJ[p]];
      float s = 0.f;
#pragma unroll
      for (int c4 = 0; c4 < 64; c4 += 4) {
        float4 a = *reinterpret_cast<const float4*>(&ri[c4]);
        float4 b = *reinterpret_cast<const float4*>(&rj[c4]);
        s += a.x * b.x + a.y * b.y + a.z * b.z + a.w * b.w;
      }
      atomicAdd(&Gram[(blockIdx.y * 8 + cl) * 28 + p], s);
    }
  }
}

// GEMM2 (MFMA split-bf16, 2-pass) + per-block Cholesky prologue + fused epilogue.
__global__ __launch_bounds__(256) void k_mf2(const u16* __restrict__ Yh, const u16* __restrict__ Yl,
                                             const u16* __restrict__ Bh,
                                             const float* __restrict__ aq,
                                             const float* __restrict__ Gram,
                                             const float* __restrict__ S,
                                             float* __restrict__ out) {
  __shared__ float Csh[4][16][68];
  __shared__ float PRo[8][15], PRd[8][6], Psv[8][6], Pb[8], Ph[8];
  int tid = threadIdx.x, w = tid >> 6, lane = tid & 63;
  int m0 = blockIdx.x * 64 + w * 16;
  int bn = blockIdx.y * 64;
  int lr = lane & 15, kof = (lane >> 4) * 8;
  const u16* ah_p = Yh + (size_t)(m0 + lr) * D + kof;
  const u16* al_p = Yl + (size_t)(m0 + lr) * D + kof;
  const u16* bh_p = Bh + (size_t)(bn + lr) * D + kof;
  f4 acc[4];
#pragma unroll
  for (int nf = 0; nf < 4; ++nf) acc[nf] = (f4){0.f, 0.f, 0.f, 0.f};
#pragma unroll 2
  for (int k0 = 0; k0 < D; k0 += 32) {
    bf8 ah = *reinterpret_cast<const bf8*>(ah_p + k0);
    bf8 al = *reinterpret_cast<const bf8*>(al_p + k0);
    bf8 bh[4];
#pragma unroll
    for (int nf = 0; nf < 4; ++nf)
      bh[nf] = *reinterpret_cast<const bf8*>(bh_p + (size_t)nf * 16 * D + k0);
#pragma unroll
    for (int nf = 0; nf < 4; ++nf)
      acc[nf] = __builtin_amdgcn_mfma_f32_16x16x32_bf16(ah, bh[nf], acc[nf], 0, 0, 0);
#pragma unroll
    for (int nf = 0; nf < 4; ++nf)
      acc[nf] = __builtin_amdgcn_mfma_f32_16x16x32_bf16(al, bh[nf], acc[nf], 0, 0, 0);
  }
#pragma unroll
  for (int reg = 0; reg < 4; ++reg)
#pragma unroll
    for (int nf = 0; nf < 4; ++nf)
      Csh[w][((lane >> 4) << 2) + reg][nf * 16 + lr] = acc[nf][reg];
  if (tid < 8) {
    int c = blockIdx.y * 8 + tid;
    float Gv[28];
#pragma unroll
    for (int p = 0; p < 28; ++p) Gv[p] = Gram[c * 28 + p];
    float R[6][6];
    float logdetM = 0.f;
#pragma unroll
    for (int i = 0; i < 6; ++i) {
      float s = Gv[GIX(i, i)] + 1.f;
#pragma unroll
      for (int k = 0; k < i; ++k) s -= R[i][k] * R[i][k];
      float rii = sqrtf(s);
      R[i][i] = rii;
      logdetM += logf(rii);
      float inv = 1.f / rii;
      PRd[tid][i] = inv;
#pragma unroll
      for (int r = i + 1; r < 6; ++r) {
        float s2 = Gv[GIX(i, r)];
#pragma unroll
        for (int k = 0; k < i; ++k) s2 -= R[r][k] * R[i][k];
        R[r][i] = s2 * inv;
      }
    }
#pragma unroll
    for (int i = 1; i < 6; ++i)
#pragma unroll
      for (int k = 0; k < i; ++k)
        PRo[tid][i * (i - 1) / 2 + k] = R[i][k];
#pragma unroll
    for (int j = 0; j < 6; ++j) Psv[tid][j] = Gv[GIX(j, 6)];
    Ph[tid] = Gv[27];
    Pb[tid] = S[3] - 0.5f * (S[9] + 2.f * logdetM);
  }
  __syncthreads();
  float s8 = S[8], s10 = S[10], s11 = S[11];
  int r = lr;
  int q = m0 + r;
  float aqv = aq[q];
#pragma unroll
  for (int cc = 0; cc < 2; ++cc) {
    int cl = ((lane >> 4) << 1) + cc;
    const float* t = &Csh[w][r][cl * 8];
    float e[6];
#pragma unroll
    for (int j = 0; j < 6; ++j) e[j] = t[j] - Psv[cl][j];
    const float* o = PRo[cl];
    const float* dg = PRd[cl];
    float z0 = e[0] * dg[0];
    float z1 = (e[1] - o[0] * z0) * dg[1];
    float z2 = (e[2] - o[1] * z0 - o[2] * z1) * dg[2];
    float z3 = (e[3] - o[3] * z0 - o[4] * z1 - o[5] * z2) * dg[3];
    float z4 = (e[4] - o[6] * z0 - o[7] * z1 - o[8] * z2 - o[9] * z3) * dg[4];
    float z5 = (e[5] - o[10] * z0 - o[11] * z1 - o[12] * z2 - o[13] * z3 - o[14] * z4) * dg[5];
    float quad = z0 * z0 + z1 * z1 + z2 * z2 + z3 * z3 + z4 * z4 + z5 * z5;
    float dist = (aqv - 2.f * t[6] + Ph[cl] - quad) * s8;
    out[(size_t)q * NC + blockIdx.y * 8 + cl] = Pb[cl] - s10 * log1pf(dist * s11);
  }
}

extern "C" void kernel_launch(void* const* d_in, const int* in_sizes, int n_in,
                              void* d_out, int out_size, void* d_ws, size_t ws_size,
                              hipStream_t stream) {
  const float* Xs   = (const float*)d_in[0];
  const float* Xq   = (const float*)d_in[2];
  const float* m    = (const float*)d_in[3];
  const float* kap  = (const float*)d_in[4];
  const float* nu   = (const float*)d_in[5];
  const float* diag = (const float*)d_in[6];
  const float* low  = (const float*)d_in[7];
  float* ws = (float*)d_ws;

  float* S    = ws + OFF_S;
  u16*   ABh  = (u16*)(ws + OFF_ABH);
  u16*   ABl  = (u16*)(ws + OFF_ABL);
  u16*   Lh   = (u16*)(ws + OFF_LH);
  u16*   Ll   = (u16*)(ws + OFF_LL);
  u16*   Wh   = (u16*)(ws + OFF_WH);
  u16*   Wl   = (u16*)(ws + OFF_WL);
  u16*   YYh  = (u16*)(ws + OFF_YYH);
  u16*   YYl  = (u16*)(ws + OFF_YYL);
  float* aq   = ws + OFF_AQ;
  float* Gram = ws + OFF_GRAM;

  hipLaunchKernelGGL(k_prep, dim3(457), dim3(256), 0, stream,
                     diag, low, Xs, Xq, m, kap, nu, Lh, Ll, ABh, ABl, Wh, Wl, S, aq, Gram);
  hipLaunchKernelGGL(k_solve, dim3(16), dim3(256), 0, stream, Lh, Ll, Wh, Wl);
  // GEMM1: YY = [Ubp;Xq] @ W^T (tri-clipped) + aq + class Grams
  hipLaunchKernelGGL(k_mf1, dim3(8, 40), dim3(256), 0, stream,
                     ABh, ABl, Wh, YYh, YYl, Gram, aq);
  // GEMM2: out = epilogue(Y @ UWp^T) with per-block Cholesky prologue
  hipLaunchKernelGGL(k_mf2, dim3(32, 8), dim3(256), 0, stream,
                     YYh + (size_t)512 * D, YYl + (size_t)512 * D, YYh,
                     aq, Gram, S, (float*)d_out);
}